// Round 4
// baseline (1782.020 us; speedup 1.0000x reference)
//
#include <hip/hip_runtime.h>

// AdaTTSp on MI355X. B=32768, T=8, E=2, NE=16, D=H=128, L=2.
// Round 4: round-3 pipeline with ONE change — d_out is FLOAT32 (the
// reference's output dtype), not bf16. Rounds 1-3 wrote u16 bf16 into a
// f32 buffer; the unwritten second half produced the bit-identical
// absmax 0.19921875 (= max |bf16(ref)| over the unwritten region).
// Pure-f32 VALU pipeline, correct-by-construction; MFMA returns next round.
// ws: eo f32 [4096][16][128] = 32MB | x1f f32 [4096][8][128] = 16MB = 48MB.

typedef unsigned short u16;

// ---------------------------------------------------------------------------
// Experts: block = 128 threads = (output col), handles 8 rows x 1 expert.
// grid = 512 row-groups * 16 experts (chunk of 4096 rows).
__global__ __launch_bounds__(128) void s_expert(
    const float* __restrict__ x0, const float* __restrict__ x1f,
    const float* __restrict__ w1, const float* __restrict__ b1,
    const float* __restrict__ w2, const float* __restrict__ b2,
    float* __restrict__ eo, int layer, int c0) {
  __shared__ __align__(16) float xs[8 * 128];
  __shared__ __align__(16) float hs[8 * 128];
  const int tid = threadIdx.x;
  const int rg = blockIdx.x & 511;
  const int e = blockIdx.x >> 9;
  const int te = e >> 1;
  const int r0 = rg * 8;  // chunk-local row base
  const int lx = layer * 16 + e;

#pragma unroll
  for (int i = 0; i < 8; ++i) {
    int lr = r0 + i;
    float v;
    if (layer == 0)
      v = x0[((size_t)(c0 + lr) * 8 + te) * 128 + tid];  // x0 [B][T][D]
    else
      v = x1f[((size_t)lr * 8 + te) * 128 + tid];  // x1f [4096][T][D]
    xs[i * 128 + tid] = v;
  }
  __syncthreads();

  // GEMM1
  const float* w1p = w1 + (size_t)lx * 16384;  // w1 [L*NE][D][H]
  float a[8];
#pragma unroll
  for (int i = 0; i < 8; ++i) a[i] = 0.f;
  const float4* xs4 = (const float4*)xs;  // [8][32]
  for (int d4 = 0; d4 < 32; ++d4) {
    float wa = w1p[(4 * d4 + 0) * 128 + tid];
    float wb = w1p[(4 * d4 + 1) * 128 + tid];
    float wc = w1p[(4 * d4 + 2) * 128 + tid];
    float wd = w1p[(4 * d4 + 3) * 128 + tid];
#pragma unroll
    for (int i = 0; i < 8; ++i) {
      float4 xv = xs4[i * 32 + d4];
      a[i] = fmaf(xv.x, wa, a[i]);
      a[i] = fmaf(xv.y, wb, a[i]);
      a[i] = fmaf(xv.z, wc, a[i]);
      a[i] = fmaf(xv.w, wd, a[i]);
    }
  }
  float bb1 = b1[lx * 128 + tid];
#pragma unroll
  for (int i = 0; i < 8; ++i) hs[i * 128 + tid] = fmaxf(a[i] + bb1, 0.f);
  __syncthreads();

  // GEMM2
  const float* w2p = w2 + (size_t)lx * 16384;  // w2 [L*NE][H][O]
#pragma unroll
  for (int i = 0; i < 8; ++i) a[i] = 0.f;
  const float4* hs4 = (const float4*)hs;
  for (int d4 = 0; d4 < 32; ++d4) {
    float wa = w2p[(4 * d4 + 0) * 128 + tid];
    float wb = w2p[(4 * d4 + 1) * 128 + tid];
    float wc = w2p[(4 * d4 + 2) * 128 + tid];
    float wd = w2p[(4 * d4 + 3) * 128 + tid];
#pragma unroll
    for (int i = 0; i < 8; ++i) {
      float4 hv = hs4[i * 32 + d4];
      a[i] = fmaf(hv.x, wa, a[i]);
      a[i] = fmaf(hv.y, wb, a[i]);
      a[i] = fmaf(hv.z, wc, a[i]);
      a[i] = fmaf(hv.w, wd, a[i]);
    }
  }
  float bb2 = b2[lx * 128 + tid];
#pragma unroll
  for (int i = 0; i < 8; ++i)
    eo[((size_t)(r0 + i) * 16 + e) * 128 + tid] = fmaxf(a[i] + bb2, 0.f);
}

// ---------------------------------------------------------------------------
// Gate + mix: block = 256 threads, one batch row per block; grid = 4096.
__global__ __launch_bounds__(256) void s_fuse(
    const float* __restrict__ x0, const float* __restrict__ x1f,
    const float* __restrict__ gw, const float* __restrict__ gb,
    const float* __restrict__ sew, const float* __restrict__ eo,
    float* __restrict__ x1out, float* __restrict__ out, int layer, int c0) {
  __shared__ __align__(16) float xs[8 * 128];
  __shared__ __align__(16) float eos[16 * 128];
  __shared__ float gs[8 * 16];
  const int tid = threadIdx.x;
  const int lr = blockIdx.x;  // chunk-local row
  const int grow = c0 + lr;   // global row

#pragma unroll
  for (int i = 0; i < 4; ++i) {
    int idx = i * 256 + tid;
    xs[idx] = (layer == 0) ? x0[(size_t)grow * 1024 + idx]
                           : x1f[(size_t)lr * 1024 + idx];
  }
#pragma unroll
  for (int i = 0; i < 8; ++i) {
    int idx = i * 256 + tid;
    eos[idx] = eo[(size_t)lr * 2048 + idx];
  }
  __syncthreads();

  if (tid < 128) {
    const int t = tid >> 4, e = tid & 15;
    const int lt = layer * 8 + t;
    const float* gwp = gw + (size_t)lt * 2048;  // gw [L*T][D][NE]
    float acc = 0.f;
    for (int d = 0; d < 128; ++d)
      acc = fmaf(xs[t * 128 + d], gwp[d * 16 + e], acc);
    acc += gb[lt * 16 + e];
    // softmax over e = 16-lane groups within the wave
    float m = acc;
    m = fmaxf(m, __shfl_xor(m, 1, 64));
    m = fmaxf(m, __shfl_xor(m, 2, 64));
    m = fmaxf(m, __shfl_xor(m, 4, 64));
    m = fmaxf(m, __shfl_xor(m, 8, 64));
    float p = __expf(acc - m);
    float s = p;
    s += __shfl_xor(s, 1, 64);
    s += __shfl_xor(s, 2, 64);
    s += __shfl_xor(s, 4, 64);
    s += __shfl_xor(s, 8, 64);
    gs[tid] = p / s;
  }
  __syncthreads();

#pragma unroll
  for (int q = 0; q < 4; ++q) {
    int idx = q * 256 + tid;  // 0..1023 = t*128 + col
    int t = idx >> 7, col = idx & 127;
    int lt = layer * 8 + t;
    float acc = 0.f;
#pragma unroll
    for (int e = 0; e < 16; ++e)
      acc = fmaf(gs[t * 16 + e], eos[e * 128 + col], acc);
    acc = fmaf(sew[lt * 2 + 0], eos[(2 * t) * 128 + col], acc);
    acc = fmaf(sew[lt * 2 + 1], eos[(2 * t + 1) * 128 + col], acc);
    if (layer == 0)
      x1out[(size_t)lr * 1024 + idx] = acc;
    else
      out[(size_t)grow * 1024 + idx] = acc;  // f32 output, per harness rule
  }
}

// ---------------------------------------------------------------------------
extern "C" void kernel_launch(void* const* d_in, const int* in_sizes, int n_in,
                              void* d_out, int out_size, void* d_ws, size_t ws_size,
                              hipStream_t stream) {
  const float* x0 = (const float*)d_in[0];
  const float* w1 = (const float*)d_in[1];
  const float* b1 = (const float*)d_in[2];
  const float* w2 = (const float*)d_in[3];
  const float* b2 = (const float*)d_in[4];
  const float* gw = (const float*)d_in[5];
  const float* gb = (const float*)d_in[6];
  const float* sw = (const float*)d_in[7];

  float* eo = (float*)d_ws;                       // 32 MB
  float* x1f = (float*)((char*)d_ws + 33554432);  // 16 MB
  float* out = (float*)d_out;                     // FLOAT32 output buffer

  for (int c = 0; c < 8; ++c) {
    int c0 = c * 4096;
    for (int l = 0; l < 2; ++l) {
      s_expert<<<8192, 128, 0, stream>>>(x0, x1f, w1, b1, w2, b2, eo, l, c0);
      s_fuse<<<4096, 256, 0, stream>>>(x0, x1f, gw, gb, sw, eo, x1f, out, l, c0);
    }
  }
}

// Round 5
// 691.366 us; speedup vs baseline: 2.5775x; 2.5775x over previous
//
#include <hip/hip_runtime.h>

// AdaTTSp on MI355X. B=32768, T=8, E=2, NE=16, D=H=128, L=2.
// Round 5: round-4 pipeline with s_expert replaced by split-precision bf16
// MFMA kernel (hi+lo pairs, 3 MFMAs per term, f32 accum). s_fuse and eo
// layout [row][e][col] f32 unchanged (validated in round 4).
// ws: w1T/w2T bf16-pair 4MB | eo f32 32MB | x1f f32 16MB = 52MB.

typedef float f32x4 __attribute__((ext_vector_type(4)));
typedef short s16x8 __attribute__((ext_vector_type(8)));
typedef unsigned short u16;
typedef u16 u16x4 __attribute__((ext_vector_type(4)));

#define MFMA(a, b, c) __builtin_amdgcn_mfma_f32_16x16x32_bf16(a, b, c, 0, 0, 0)

__device__ __forceinline__ u16 f2bf(float f) {
  unsigned u = __builtin_bit_cast(unsigned, f);
  return (u16)((u + 0x7FFFu + ((u >> 16) & 1u)) >> 16);  // RNE
}
__device__ __forceinline__ float bf2f(u16 b) {
  unsigned u = ((unsigned)b) << 16;
  return __builtin_bit_cast(float, u);
}
__device__ __forceinline__ void split2(float f, u16& h, u16& l) {
  h = f2bf(f);
  l = f2bf(f - bf2f(h));
}

// ---------------------------------------------------------------------------
// Weight transform -> hi/lo bf16 fragment arrays (lo at +524288 elems).
// wT[q][ks][it][lane][j] = w[q][d = 32*ks + 8*(lane>>4) + j][m = 16*it + (lane&15)]
// == A-fragment (A = w^T) for output tile it, k-step ks: row=lane&15, k=8g+j.
__global__ __launch_bounds__(256) void kxform(
    const float* __restrict__ w1, const float* __restrict__ w2,
    u16* __restrict__ w1T, u16* __restrict__ w2T) {
  int idx = blockIdx.x * 256 + threadIdx.x;  // 0..131071
  const float* src = (idx < 65536) ? w1 : w2;
  u16* dst = (idx < 65536) ? w1T : w2T;
  int i = idx & 65535;
  int lane = i & 63;
  int it = (i >> 6) & 7;
  int ks = (i >> 9) & 3;
  int q = i >> 11;  // l*16 + e, 0..31
  int g = lane >> 4, le = lane & 15;
  s16x8 vh, vl;
#pragma unroll
  for (int j = 0; j < 8; ++j) {
    float f = src[((size_t)q * 128 + (32 * ks + 8 * g + j)) * 128 + 16 * it + le];
    u16 h, l;
    split2(f, h, l);
    vh[j] = (short)h;
    vl[j] = (short)l;
  }
  *(s16x8*)(dst + (size_t)i * 8) = vh;
  *(s16x8*)(dst + 524288 + (size_t)i * 8) = vl;
}

// ---------------------------------------------------------------------------
// Expert kernel, chunk of 4096 rows. grid = 32 row-blocks * 16 experts.
// 4 waves: (mh = out-dim half, nh = brow half), each wave 64x64 of C.
// GEMMs operand-swapped: C = W^T * X^T. Split precision: 3 MFMAs/term.
// LDS tile layout (both x and h): element [row][c] at
//   row*128 + 8*((c>>3) ^ (row&7)) + (c&7)   (16B-granule XOR swizzle).
__global__ __launch_bounds__(256, 2) void kexpert(
    const float* __restrict__ x0, const float* __restrict__ x1f,
    const u16* __restrict__ w1T, const u16* __restrict__ w2T,
    const float* __restrict__ b1, const float* __restrict__ b2,
    float* __restrict__ eo, int layer, int c0) {
  __shared__ u16 sAh[128 * 128];
  __shared__ u16 sAl[128 * 128];
  const int tid = threadIdx.x;
  const int lane = tid & 63;
  const int wave = tid >> 6;
  const int g = lane >> 4, le = lane & 15;
  const int mh = wave >> 1, nh = wave & 1;
  const int rb = blockIdx.x & 31;
  const int e = blockIdx.x >> 5;
  const int te = e >> 1;
  const int r0 = rb * 128;  // chunk-local row base
  const int lx = layer * 16 + e;
  const float* xsrc = (layer == 0) ? (x0 + (size_t)c0 * 1024) : x1f;

  // ---- stage x[r0..r0+127, te, :] (f32) -> bf16 hi/lo LDS tile
#pragma unroll
  for (int it8 = 0; it8 < 8; ++it8) {
    int chunk = it8 * 256 + tid;
    int row = chunk >> 4, kb = chunk & 15;
    const float* p = xsrc + ((size_t)(r0 + row) * 8 + te) * 128 + kb * 8;
    f32x4 f0 = *(const f32x4*)p;
    f32x4 f1 = *(const f32x4*)(p + 4);
    s16x8 vh, vl;
#pragma unroll
    for (int z = 0; z < 4; ++z) {
      u16 h, l;
      split2(f0[z], h, l);
      vh[z] = (short)h;
      vl[z] = (short)l;
      split2(f1[z], h, l);
      vh[4 + z] = (short)h;
      vl[4 + z] = (short)l;
    }
    int sa = (row * 16 + (kb ^ (row & 7))) * 8;
    *(s16x8*)(sAh + sa) = vh;
    *(s16x8*)(sAl + sa) = vl;
  }
  __syncthreads();

  f32x4 acc[4][4];
  // ---- GEMM1: hT[hdim][brow] = w1^T x^T, K = 128.
#pragma unroll
  for (int i = 0; i < 4; ++i)
#pragma unroll
    for (int j = 0; j < 4; ++j) acc[i][j] = f32x4{0.f, 0.f, 0.f, 0.f};
#pragma unroll
  for (int ks = 0; ks < 4; ++ks) {
    s16x8 ah[4], al[4];
#pragma unroll
    for (int i = 0; i < 4; ++i) {
      size_t fb = ((size_t)((lx * 4 + ks) * 8 + 4 * mh + i) * 64 + lane) * 8;
      ah[i] = *(const s16x8*)(w1T + fb);
      al[i] = *(const s16x8*)(w1T + 524288 + fb);
    }
#pragma unroll
    for (int j = 0; j < 4; ++j) {
      int row = 16 * (4 * nh + j) + le;
      int sa = (row * 16 + ((4 * ks + g) ^ (le & 7))) * 8;
      s16x8 bh = *(const s16x8*)(sAh + sa);
      s16x8 bl = *(const s16x8*)(sAl + sa);
#pragma unroll
      for (int i = 0; i < 4; ++i) {
        acc[i][j] = MFMA(al[i], bh, acc[i][j]);
        acc[i][j] = MFMA(ah[i], bl, acc[i][j]);
        acc[i][j] = MFMA(ah[i], bh, acc[i][j]);
      }
    }
  }
  __syncthreads();  // all x reads done before overwrite with h

  // ---- epilogue 1: h = relu(hT + b1) -> same LDS tile (hi/lo)
#pragma unroll
  for (int i = 0; i < 4; ++i) {
    f32x4 bv = *(const f32x4*)(b1 + lx * 128 + 64 * mh + 16 * i + 4 * g);
#pragma unroll
    for (int j = 0; j < 4; ++j) {
      int brow = 16 * (4 * nh + j) + le;
      u16x4 hh, hl;
#pragma unroll
      for (int r = 0; r < 4; ++r) {
        float f = fmaxf(acc[i][j][r] + bv[r], 0.f);
        u16 h, l;
        split2(f, h, l);
        hh[r] = h;
        hl[r] = l;
      }
      int col = 64 * mh + 16 * i + 4 * g;
      int addr = brow * 128 + (col ^ ((le & 7) << 3));
      *(u16x4*)(sAh + addr) = hh;
      *(u16x4*)(sAl + addr) = hl;
    }
  }
  __syncthreads();

  // ---- GEMM2: eoT[oc][brow] = w2^T h^T, K = 128.
#pragma unroll
  for (int i = 0; i < 4; ++i)
#pragma unroll
    for (int j = 0; j < 4; ++j) acc[i][j] = f32x4{0.f, 0.f, 0.f, 0.f};
#pragma unroll
  for (int ks = 0; ks < 4; ++ks) {
    s16x8 ah[4], al[4];
#pragma unroll
    for (int i = 0; i < 4; ++i) {
      size_t fb = ((size_t)((lx * 4 + ks) * 8 + 4 * mh + i) * 64 + lane) * 8;
      ah[i] = *(const s16x8*)(w2T + fb);
      al[i] = *(const s16x8*)(w2T + 524288 + fb);
    }
#pragma unroll
    for (int j = 0; j < 4; ++j) {
      int row = 16 * (4 * nh + j) + le;
      int sa = (row * 16 + ((4 * ks + g) ^ (le & 7))) * 8;
      s16x8 bh = *(const s16x8*)(sAh + sa);
      s16x8 bl = *(const s16x8*)(sAl + sa);
#pragma unroll
      for (int i = 0; i < 4; ++i) {
        acc[i][j] = MFMA(al[i], bh, acc[i][j]);
        acc[i][j] = MFMA(ah[i], bl, acc[i][j]);
        acc[i][j] = MFMA(ah[i], bh, acc[i][j]);
      }
    }
  }
  // ---- epilogue 2: eo[lr][e][oc] = relu(+b2), f32 (round-4 layout).
#pragma unroll
  for (int i = 0; i < 4; ++i) {
    f32x4 bv = *(const f32x4*)(b2 + lx * 128 + 64 * mh + 16 * i + 4 * g);
#pragma unroll
    for (int j = 0; j < 4; ++j) {
      int lr = r0 + 16 * (4 * nh + j) + le;
      int oc = 64 * mh + 16 * i + 4 * g;
      f32x4 ev;
#pragma unroll
      for (int r = 0; r < 4; ++r) ev[r] = fmaxf(acc[i][j][r] + bv[r], 0.f);
      *(f32x4*)(eo + ((size_t)lr * 16 + e) * 128 + oc) = ev;
    }
  }
}

// ---------------------------------------------------------------------------
// Gate + mix: block = 256 threads, one batch row per block; grid = 4096.
// (unchanged from round 4 — validated)
__global__ __launch_bounds__(256) void s_fuse(
    const float* __restrict__ x0, const float* __restrict__ x1f,
    const float* __restrict__ gw, const float* __restrict__ gb,
    const float* __restrict__ sew, const float* __restrict__ eo,
    float* __restrict__ x1out, float* __restrict__ out, int layer, int c0) {
  __shared__ __align__(16) float xs[8 * 128];
  __shared__ __align__(16) float eos[16 * 128];
  __shared__ float gs[8 * 16];
  const int tid = threadIdx.x;
  const int lr = blockIdx.x;  // chunk-local row
  const int grow = c0 + lr;   // global row

#pragma unroll
  for (int i = 0; i < 4; ++i) {
    int idx = i * 256 + tid;
    xs[idx] = (layer == 0) ? x0[(size_t)grow * 1024 + idx]
                           : x1f[(size_t)lr * 1024 + idx];
  }
#pragma unroll
  for (int i = 0; i < 8; ++i) {
    int idx = i * 256 + tid;
    eos[idx] = eo[(size_t)lr * 2048 + idx];
  }
  __syncthreads();

  if (tid < 128) {
    const int t = tid >> 4, e = tid & 15;
    const int lt = layer * 8 + t;
    const float* gwp = gw + (size_t)lt * 2048;  // gw [L*T][D][NE]
    float acc = 0.f;
    for (int d = 0; d < 128; ++d)
      acc = fmaf(xs[t * 128 + d], gwp[d * 16 + e], acc);
    acc += gb[lt * 16 + e];
    float m = acc;
    m = fmaxf(m, __shfl_xor(m, 1, 64));
    m = fmaxf(m, __shfl_xor(m, 2, 64));
    m = fmaxf(m, __shfl_xor(m, 4, 64));
    m = fmaxf(m, __shfl_xor(m, 8, 64));
    float p = __expf(acc - m);
    float s = p;
    s += __shfl_xor(s, 1, 64);
    s += __shfl_xor(s, 2, 64);
    s += __shfl_xor(s, 4, 64);
    s += __shfl_xor(s, 8, 64);
    gs[tid] = p / s;
  }
  __syncthreads();

#pragma unroll
  for (int q = 0; q < 4; ++q) {
    int idx = q * 256 + tid;  // t*128 + col
    int t = idx >> 7, col = idx & 127;
    int lt = layer * 8 + t;
    float acc = 0.f;
#pragma unroll
    for (int e = 0; e < 16; ++e)
      acc = fmaf(gs[t * 16 + e], eos[e * 128 + col], acc);
    acc = fmaf(sew[lt * 2 + 0], eos[(2 * t) * 128 + col], acc);
    acc = fmaf(sew[lt * 2 + 1], eos[(2 * t + 1) * 128 + col], acc);
    if (layer == 0)
      x1out[(size_t)lr * 1024 + idx] = acc;
    else
      out[(size_t)grow * 1024 + idx] = acc;
  }
}

// ---------------------------------------------------------------------------
extern "C" void kernel_launch(void* const* d_in, const int* in_sizes, int n_in,
                              void* d_out, int out_size, void* d_ws, size_t ws_size,
                              hipStream_t stream) {
  const float* x0 = (const float*)d_in[0];
  const float* w1 = (const float*)d_in[1];
  const float* b1 = (const float*)d_in[2];
  const float* w2 = (const float*)d_in[3];
  const float* b2 = (const float*)d_in[4];
  const float* gw = (const float*)d_in[5];
  const float* gb = (const float*)d_in[6];
  const float* sw = (const float*)d_in[7];

  // ws: w1T pair @0 (1048576 u16) | w2T pair @1048576 | eo f32 @byte 4194304
  // (32MB) | x1f f32 @byte 37748736 (16MB). Total 52MB.
  u16* w1T = (u16*)d_ws;
  u16* w2T = w1T + 1048576;
  float* eo = (float*)((char*)d_ws + 4194304);
  float* x1f = (float*)((char*)d_ws + 37748736);
  float* out = (float*)d_out;

  kxform<<<512, 256, 0, stream>>>(w1, w2, w1T, w2T);

  for (int c = 0; c < 8; ++c) {
    int c0 = c * 4096;
    for (int l = 0; l < 2; ++l) {
      kexpert<<<512, 256, 0, stream>>>(x0, x1f, w1T, w2T, b1, b2, eo, l, c0);
      s_fuse<<<4096, 256, 0, stream>>>(x0, x1f, gw, gb, sw, eo, x1f, out, l, c0);
    }
  }
}